// Round 1
// baseline (165.276 us; speedup 1.0000x reference)
//
#include <hip/hip_runtime.h>
#include <hip/hip_bf16.h>
#include <stdint.h>

typedef __bf16 bf16_t;
typedef __bf16 bf16x8 __attribute__((ext_vector_type(8)));
typedef __bf16 bf16x4 __attribute__((ext_vector_type(4)));
typedef float  f32x4  __attribute__((ext_vector_type(4)));

#define DIM   1024
#define BATCH 8
#define NTOK  (BATCH * DIM)   /* 8192 */
#define SCALE 0.03125f        /* 1/sqrt(1024) */

// ---------------- f32 -> bf16 convert (vectorized) ----------------
__global__ void k_cvt(const float* __restrict__ in, bf16_t* __restrict__ out, int n4) {
    int i = blockIdx.x * blockDim.x + threadIdx.x;
    if (i < n4) {
        const float4 v = reinterpret_cast<const float4*>(in)[i];
        bf16x4 o;
        o.x = (bf16_t)v.x; o.y = (bf16_t)v.y; o.z = (bf16_t)v.z; o.w = (bf16_t)v.w;
        reinterpret_cast<bf16x4*>(out)[i] = o;
    }
}

// ------------- W_eff^T[e][d] = bf16( sum_n w[n][d][e] ) -------------
__global__ void k_weff(const float* __restrict__ w, bf16_t* __restrict__ wt) {
    __shared__ float tile[32][33];
    const int tx = threadIdx.x & 31;
    const int ty = threadIdx.x >> 5;           // 0..7
    const int d0 = blockIdx.x * 32;
    const int e0 = blockIdx.y * 32;
#pragma unroll
    for (int r = 0; r < 4; ++r) {
        const int d = d0 + r * 8 + ty;
        const int e = e0 + tx;
        tile[r * 8 + ty][tx] =
            w[d * 1024 + e] + w[1048576 + d * 1024 + e] + w[2097152 + d * 1024 + e];
    }
    __syncthreads();
#pragma unroll
    for (int r = 0; r < 4; ++r) {
        const int e = e0 + r * 8 + ty;
        const int d = d0 + tx;
        wt[e * 1024 + d] = (bf16_t)tile[tx][r * 8 + ty];
    }
}

// ---------------- 128x128 tile bf16 MFMA GEMM, B^T layout ----------------
// C[m][n] = sum_k A[m][k] * B[n][k]
// MODE 0: oB[m*1024+n] = bf16(acc)                      (qw = q @ Weff)
// MODE 1: acc += bias[n]; n>>10 routes to q/k bf16 or v f32 (d_out)
// MODE 2: oF[z*1M + m*1024+n] += SCALE*acc              (scores, += onto v)
template<int MODE>
__global__ __launch_bounds__(256)
void k_gemm(const bf16_t* __restrict__ A, const bf16_t* __restrict__ B, int K,
            const float* __restrict__ bias,
            bf16_t* __restrict__ oQ, bf16_t* __restrict__ oK,
            float* __restrict__ oF, bf16_t* __restrict__ oB)
{
    __shared__ __align__(16) bf16_t As[128 * 32];
    __shared__ __align__(16) bf16_t Bs[128 * 32];

    const int tid  = threadIdx.x;
    const int wave = tid >> 6;
    const int lane = tid & 63;
    const int wr = wave >> 1, wc = wave & 1;
    const int lhi = lane >> 4, llo = lane & 15;

    const int bm = blockIdx.x * 128;
    const int bn = blockIdx.y * 128;
    const long zAB = (MODE == 2) ? (long)blockIdx.z * (DIM * DIM) : 0;

    f32x4 acc[4][4];
    const f32x4 fz = {0.f, 0.f, 0.f, 0.f};
#pragma unroll
    for (int i = 0; i < 4; ++i)
#pragma unroll
        for (int j = 0; j < 4; ++j) acc[i][j] = fz;

    for (int k0 = 0; k0 < K; k0 += 32) {
        // ---- stage A,B tiles (128x32 bf16 = 8KB each) via global_load_lds ----
#pragma unroll
        for (int i = 0; i < 2; ++i) {
            const int c  = wave * 128 + i * 64 + lane;   // 16B chunk id, 0..511
            const int r  = c >> 2;
            const int cc = (c & 3) << 3;
            const long ga = zAB + (long)(bm + r) * K + (k0 + cc);
            const long gb = zAB + (long)(bn + r) * K + (k0 + cc);
            const int lbase = (wave * 128 + i * 64) << 3;  // wave-uniform elem offset
            __builtin_amdgcn_global_load_lds(
                (const __attribute__((address_space(1))) uint32_t*)(A + ga),
                (__attribute__((address_space(3))) uint32_t*)(&As[lbase]), 16, 0, 0);
            __builtin_amdgcn_global_load_lds(
                (const __attribute__((address_space(1))) uint32_t*)(B + gb),
                (__attribute__((address_space(3))) uint32_t*)(&Bs[lbase]), 16, 0, 0);
        }
        __syncthreads();

        bf16x8 af[4], bfr[4];
#pragma unroll
        for (int mi = 0; mi < 4; ++mi)
            af[mi] = *reinterpret_cast<const bf16x8*>(&As[(wr * 64 + mi * 16 + llo) * 32 + lhi * 8]);
#pragma unroll
        for (int ni = 0; ni < 4; ++ni)
            bfr[ni] = *reinterpret_cast<const bf16x8*>(&Bs[(wc * 64 + ni * 16 + llo) * 32 + lhi * 8]);
#pragma unroll
        for (int mi = 0; mi < 4; ++mi)
#pragma unroll
            for (int ni = 0; ni < 4; ++ni)
                acc[mi][ni] = __builtin_amdgcn_mfma_f32_16x16x32_bf16(af[mi], bfr[ni], acc[mi][ni], 0, 0, 0);
        __syncthreads();
    }

    // ---------------- epilogue ----------------
#pragma unroll
    for (int mi = 0; mi < 4; ++mi) {
        const int r0 = bm + wr * 64 + mi * 16 + lhi * 4;
#pragma unroll
        for (int ni = 0; ni < 4; ++ni) {
            const int cg = bn + wc * 64 + ni * 16 + llo;
            const f32x4 v = acc[mi][ni];
#pragma unroll
            for (int j = 0; j < 4; ++j) {
                const long row = r0 + j;
                if (MODE == 1) {
                    const float val = v[j] + bias[cg];
                    const int  sec = cg >> 10;
                    const long idx = row * DIM + (cg & 1023);
                    if (sec == 0)      oQ[idx] = (bf16_t)val;
                    else if (sec == 1) oK[idx] = (bf16_t)val;
                    else               oF[idx] = val;
                } else if (MODE == 0) {
                    oB[row * DIM + cg] = (bf16_t)v[j];
                } else {
                    const long idx = (long)blockIdx.z * (DIM * DIM) + row * DIM + cg;
                    oF[idx] = oF[idx] + SCALE * v[j];
                }
            }
        }
    }
}

extern "C" void kernel_launch(void* const* d_in, const int* in_sizes, int n_in,
                              void* d_out, int out_size, void* d_ws, size_t ws_size,
                              hipStream_t stream) {
    const float* x    = (const float*)d_in[0];
    const float* Wqkv = (const float*)d_in[1];
    const float* bqkv = (const float*)d_in[2];
    const float* w    = (const float*)d_in[3];
    float* out = (float*)d_out;

    // workspace layout (56 MiB total)
    char* ws = (char*)d_ws;
    bf16_t* xb_qw = (bf16_t*)(ws);                         // 16 MiB: x_bf16, reused as qw_bf16
    bf16_t* qb    = (bf16_t*)(ws + (1l << 24));            // 16 MiB
    bf16_t* kb    = (bf16_t*)(ws + (2l << 24));            // 16 MiB
    bf16_t* wqb   = (bf16_t*)(ws + (3l << 24));            // 6 MiB
    bf16_t* wtb   = (bf16_t*)(ws + (3l << 24) + 6291456);  // 2 MiB
    if (ws_size < (size_t)(3l << 24) + 6291456 + 2097152) return;

    // converts + W_eff^T
    k_cvt <<<dim3(NTOK * DIM / 4 / 256), dim3(256), 0, stream>>>(x, xb_qw, NTOK * DIM / 4);
    k_cvt <<<dim3(3 * DIM * DIM / 4 / 256), dim3(256), 0, stream>>>(Wqkv, wqb, 3 * DIM * DIM / 4);
    k_weff<<<dim3(32, 32), dim3(256), 0, stream>>>(w, wtb);

    // GEMM1: qkv = x @ Wqkv^T + b  -> q,k (bf16) ; v (f32) -> d_out
    k_gemm<1><<<dim3(NTOK / 128, 3 * DIM / 128), dim3(256), 0, stream>>>(
        xb_qw, wqb, DIM, bqkv, qb, kb, out, nullptr);
    // GEMM2: qw = q @ Weff  (B = Weff^T rows)
    k_gemm<0><<<dim3(NTOK / 128, DIM / 128), dim3(256), 0, stream>>>(
        qb, wtb, DIM, nullptr, nullptr, nullptr, nullptr, xb_qw);
    // GEMM3: out += SCALE * qw @ k^T   (per batch)
    k_gemm<2><<<dim3(DIM / 128, DIM / 128, BATCH), dim3(256), 0, stream>>>(
        xb_qw, kb, DIM, nullptr, nullptr, nullptr, out, nullptr);
}